// Round 7
// baseline (326.754 us; speedup 1.0000x reference)
//
#include <hip/hip_runtime.h>
#include <hip/hip_fp16.h>
#include <math.h>

#define NNODES 100000
#define NT0 60000
#define NT1 40000
#define FD0 128
#define FD1 64
#define HID 64
#define HEADS 8
#define OUTD 16
#define AVEC 128
#define NE 250000
#define NG 8192
#define NB 8192

// workspace layout (float offsets)
#define OFF_TF16    0ull          // 100000*64 halves = 3,200,000 floats
#define OFF_FINALS  3200000ull    // 512
#define OFF_A       3200512ull    // 3,072
#define OFF_ACC     3203584ull    // 256
#define OFF_BETA    3203840ull    // 256
#define OFF_P       3204096ull    // 2,400,000 floats = 4,800,000 halves
#define OFF_SORTED  5604096ull    // 2,000,000 (500,000 int4)
#define OFF_COUNTS  7604096ull    // 16,384 ints (dst histograms, both p)
#define OFF_CNTT    7620480ull    // 16,384 ints (tgt histograms, both p) -- contiguous with COUNTS
#define OFF_CURS    7636864ull    // 16,384 ints
#define OFF_OFFS    7653248ull    // 16,640 ints (16,385 used)
#define OFF_FT      7669888ull    // 2*NG*512 = 8,388,608
// total = 16,058,496 floats = 64.2 MB

// ---- prep: finals + logit-projection matrices A, zero acc ----
__global__ __launch_bounds__(256) void k_prep(const float* __restrict__ r_vec,
                       const float* __restrict__ attn0, const float* __restrict__ attn1,
                       float* __restrict__ finals, float* __restrict__ A,
                       float* __restrict__ acc, float* __restrict__ beta){
  __shared__ float2 fl[192];   // [pi][pair]
  int t = threadIdx.x;
  if (t < 32){
    int j = t;
    const float2* rv = (const float2*)r_vec;
    float2 r0 = rv[j];
    float2 r1 = rv[32 + j];
    float n0 = rsqrtf(r0.x*r0.x + r0.y*r0.y);
    float n1 = rsqrtf(r1.x*r1.x + r1.y*r1.y);
    r0.x *= n0; r0.y *= n0; r1.x *= n1; r1.y *= n1;
    float2 rf1 = make_float2(r0.x, -r0.y);   // conj(r0)
    float2 rf3 = make_float2(r1.x, -r1.y);   // conj(r1)
    float2 F00 = make_float2(rf1.x*r0.x - rf1.y*r0.y, rf1.x*r0.y + rf1.y*r0.x);
    float2 F10 = make_float2(rf3.x*r1.x - rf3.y*r1.y, rf3.x*r1.y + rf3.y*r1.x);
    float2 one = make_float2(1.f, 0.f);
    float2* F = (float2*)finals;
    F[0*32+j] = F00; F[1*32+j] = rf1; F[2*32+j] = one;
    F[3*32+j] = F10; F[4*32+j] = rf3; F[5*32+j] = one;
    fl[0*32+j] = F00; fl[1*32+j] = rf1; fl[2*32+j] = one;
    fl[3*32+j] = F10; fl[4*32+j] = rf3; fl[5*32+j] = one;
  }
  __syncthreads();
  for (int idx = t; idx < 1536; idx += 256){
    int pair = idx & 31, k = (idx >> 5) & 7, pi = idx >> 8;   // pi 0..5
    const float* at = (pi >= 3) ? attn1 : attn0;
    float2 f = fl[pi*32 + pair];
    float a0 = at[k*64 + 2*pair], a1 = at[k*64 + 2*pair + 1];
    A[(pi*8+k)*64 + 2*pair]     = (f.x*a0 + f.y*a1) * (1.f/3.f);
    A[(pi*8+k)*64 + 2*pair + 1] = (f.x*a1 - f.y*a0) * (1.f/3.f);
  }
  acc[t] = 0.f;
  if (t < 2) beta[t] = 0.f;
}

// ---- merged per-type linear: tf16[idx[m]] = f16(feat[m] @ W.T + b) ----
__global__ __launch_bounds__(256) void k_transform2(const float* __restrict__ feat0,
                  const float* __restrict__ W0v, const float* __restrict__ b0v,
                  const int* __restrict__ idx0,
                  const float* __restrict__ feat1, const float* __restrict__ W1v,
                  const float* __restrict__ b1v, const int* __restrict__ idx1,
                  __half* __restrict__ tf16){
  __shared__ float Ax[32][68];
  __shared__ float Bs[32][68];
  const int nb0 = (NT0 + 63)/64;
  int bid = blockIdx.x;
  const float *feat, *W, *bias; const int* idx; int n_nodes, F, m0;
  if (bid < nb0){ feat=feat0; W=W0v; bias=b0v; idx=idx0; n_nodes=NT0; F=FD0; m0=bid*64; }
  else { feat=feat1; W=W1v; bias=b1v; idx=idx1; n_nodes=NT1; F=FD1; m0=(bid-nb0)*64; }
  int t = threadIdx.x;
  int tx = t & 15;
  int ty = t >> 4;
  int Fq = F >> 2;

  float acc[4][4];
  #pragma unroll
  for (int i = 0; i < 4; ++i)
    #pragma unroll
    for (int j = 0; j < 4; ++j) acc[i][j] = 0.f;

  const float4* feat4 = (const float4*)feat;
  const float4* W4 = (const float4*)W;

  for (int k0 = 0; k0 < F; k0 += 32){
    #pragma unroll
    for (int qq = 0; qq < 2; ++qq){
      int q = t + qq*256;
      int m = q >> 3, kq = q & 7;
      int gm = m0 + m; if (gm > n_nodes - 1) gm = n_nodes - 1;
      float4 v = feat4[(size_t)gm*Fq + (k0 >> 2) + kq];
      Ax[kq*4+0][m] = v.x; Ax[kq*4+1][m] = v.y; Ax[kq*4+2][m] = v.z; Ax[kq*4+3][m] = v.w;
    }
    #pragma unroll
    for (int qq = 0; qq < 2; ++qq){
      int q = t + qq*256;
      int d = q >> 3, kq = q & 7;
      float4 v = W4[(size_t)d*Fq + (k0 >> 2) + kq];
      Bs[kq*4+0][d] = v.x; Bs[kq*4+1][d] = v.y; Bs[kq*4+2][d] = v.z; Bs[kq*4+3][d] = v.w;
    }
    __syncthreads();
    #pragma unroll
    for (int kk = 0; kk < 32; ++kk){
      float4 a = *(const float4*)&Ax[kk][tx*4];
      float4 b = *(const float4*)&Bs[kk][ty*4];
      acc[0][0] += a.x*b.x; acc[0][1] += a.x*b.y; acc[0][2] += a.x*b.z; acc[0][3] += a.x*b.w;
      acc[1][0] += a.y*b.x; acc[1][1] += a.y*b.y; acc[1][2] += a.y*b.z; acc[1][3] += a.y*b.w;
      acc[2][0] += a.z*b.x; acc[2][1] += a.z*b.y; acc[2][2] += a.z*b.z; acc[2][3] += a.z*b.w;
      acc[3][0] += a.w*b.x; acc[3][1] += a.w*b.y; acc[3][2] += a.w*b.z; acc[3][3] += a.w*b.w;
    }
    __syncthreads();
  }

  float4 bv = *(const float4*)&bias[ty*4];
  #pragma unroll
  for (int i = 0; i < 4; ++i){
    int gm = m0 + tx*4 + i;
    if (gm < n_nodes){
      union { __half2 h2[2]; uint2 u; } pk;
      pk.h2[0] = __floats2half2_rn(acc[i][0] + bv.x, acc[i][1] + bv.y);
      pk.h2[1] = __floats2half2_rn(acc[i][2] + bv.z, acc[i][3] + bv.w);
      *(uint2*)&tf16[(size_t)idx[gm]*HID + ty*4] = pk.u;
    }
  }
}

// ---- P = tf16 @ A.T per metapath/position, stored f16 ----
__global__ __launch_bounds__(256) void k_pmat(const __half* __restrict__ tf16,
                                              const float* __restrict__ A,
                                              __half* __restrict__ P){
  __shared__ float tfl[64][65];
  __shared__ float Al[48][65];
  int t = threadIdx.x;
  int n0 = blockIdx.x * 64;
  for (int q = t; q < 3072; q += 256) Al[q >> 6][q & 63] = A[q];
  const __half2* tfh = (const __half2*)(tf16 + (size_t)n0*64);
  for (int q = t; q < 2048; q += 256){
    int n = q >> 5, dq = q & 31;
    float2 v = make_float2(0.f, 0.f);
    if (n0 + n < NNODES) v = __half22float2(tfh[n*32 + dq]);
    tfl[n][dq*2] = v.x; tfl[n][dq*2+1] = v.y;
  }
  __syncthreads();
  int nl = t >> 2, q = t & 3;
  float s[12];
  #pragma unroll
  for (int c = 0; c < 12; ++c) s[c] = 0.f;
  #pragma unroll 4
  for (int d = 0; d < 64; ++d){
    float tv = tfl[nl][d];
    #pragma unroll
    for (int c = 0; c < 12; ++c) s[c] += tv * Al[q*12 + c][d];
  }
  int gn = n0 + nl;
  if (gn < NNODES){
    #pragma unroll
    for (int c = 0; c < 12; ++c){
      int cg = q*12 + c;
      int p = cg >= 24;
      int w = cg - p*24;
      P[(size_t)p*2400000 + (size_t)gn*24 + w] = __float2half(s[c]);
    }
  }
}

// ---- zero int buffer ----
__global__ void k_zeroi(int* __restrict__ p, int n){
  int t = blockIdx.x*blockDim.x + threadIdx.x;
  if (t < n) p[t] = 0;
}

// ---- histograms: dst (both p) + tgt (both p) ----
__global__ void k_hist3(const int* __restrict__ d0, const int* __restrict__ d1,
                        const int* __restrict__ t0, const int* __restrict__ t1,
                        int* __restrict__ counts, int* __restrict__ cntt){
  int e = blockIdx.x*blockDim.x + threadIdx.x;
  if (e < NE) atomicAdd(&counts[d0[e]], 1);
  else if (e < 2*NE) atomicAdd(&counts[NG + d1[e-NE]], 1);
  else if (e < 2*NE + NB) atomicAdd(&cntt[t0[e-2*NE]], 1);
  else if (e < 2*NE + 2*NB) atomicAdd(&cntt[NG + t1[e-2*NE-NB]], 1);
}

// ---- exclusive scan over 16384 counts; also zero cursors ----
__global__ __launch_bounds__(1024) void k_scan(const int* __restrict__ counts,
                                               int* __restrict__ offs,
                                               int* __restrict__ curs){
  __shared__ int lds[1024];
  int t = threadIdx.x;
  int base = t*16;
  int v[16]; int sum = 0;
  #pragma unroll
  for (int i = 0; i < 16; ++i){ v[i] = counts[base+i]; sum += v[i]; }
  lds[t] = sum;
  __syncthreads();
  for (int off = 1; off < 1024; off <<= 1){
    int x = (t >= off) ? lds[t-off] : 0;
    __syncthreads();
    lds[t] += x;
    __syncthreads();
  }
  int excl = lds[t] - sum;
  #pragma unroll
  for (int i = 0; i < 16; ++i){ offs[base+i] = excl; excl += v[i]; curs[base+i] = 0; }
  if (t == 1023) offs[2*NG] = excl;
}

// ---- scatter both metapaths' edges into dst-sorted order ----
__global__ void k_scatter2(const int* __restrict__ m0, const int* __restrict__ d0,
                           const int* __restrict__ m1, const int* __restrict__ d1,
                           const int* __restrict__ offs, int* __restrict__ curs,
                           int4* __restrict__ sorted){
  int e = blockIdx.x*blockDim.x + threadIdx.x;
  if (e >= 2*NE) return;
  const int* mp; int d;
  if (e < NE){ mp = m0 + (size_t)e*3; d = d0[e]; }
  else { mp = m1 + (size_t)(e-NE)*3; d = NG + d1[e-NE]; }
  int pos = offs[d] + atomicAdd(&curs[d], 1);
  sorted[pos] = make_int4(mp[0], mp[1], mp[2], 0);
}

// ---- fused per-segment softmax-agg, both metapaths in one grid ----
__global__ __launch_bounds__(64) void k_seg(const __half* __restrict__ tf16,
                                            const __half* __restrict__ P,
                                            const int4* __restrict__ sorted,
                                            const int* __restrict__ offs,
                                            const float* __restrict__ finals,
                                            float* __restrict__ ft){
  int bid = blockIdx.x;
  int p = bid >> 13;
  int lane = threadIdx.x;
  int hw = lane >> 5, j = lane & 31;
  int start = offs[bid], end = offs[bid+1];
  float2* ftw = (float2*)(ft + (size_t)bid*512);
  if (start == end){
    #pragma unroll
    for (int kk = 0; kk < 4; ++kk) ftw[(hw*4+kk)*32 + j] = make_float2(0.f, 0.f);
    return;
  }
  const float2* F2 = (const float2*)(finals + p*192);
  float2 f0 = F2[j], f1 = F2[32 + j];
  const __half2* tfh = (const __half2*)tf16;
  const __half* Pp = P + (size_t)p*2400000;

  __shared__ int4 ndb[64];
  __shared__ float wb[64][8];

  float s[8], ur[8], ui[8];
  #pragma unroll
  for (int k = 0; k < 8; ++k){ s[k] = 0.f; ur[k] = 0.f; ui[k] = 0.f; }

  for (int c = start; c < end; c += 64){
    int n = end - c; if (n > 64) n = 64;
    if (lane < n){
      int4 nd = sorted[c + lane];
      ndb[lane] = nd;
      float4 rA = *(const float4*)(Pp + (size_t)nd.x*24);
      float4 rB = *(const float4*)(Pp + (size_t)nd.y*24 + 8);
      float4 rC = *(const float4*)(Pp + (size_t)nd.z*24 + 16);
      const __half2* ha = (const __half2*)&rA;
      const __half2* hb = (const __half2*)&rB;
      const __half2* hc = (const __half2*)&rC;
      float w[8];
      #pragma unroll
      for (int m = 0; m < 4; ++m){
        float2 va = __half22float2(ha[m]);
        float2 vb = __half22float2(hb[m]);
        float2 vc = __half22float2(hc[m]);
        float x0 = va.x + vb.x + vc.x;
        float x1 = va.y + vb.y + vc.y;
        x0 = x0 > 0.f ? x0 : 0.01f*x0;
        x1 = x1 > 0.f ? x1 : 0.01f*x1;
        w[2*m]   = __expf(x0);
        w[2*m+1] = __expf(x1);
      }
      *(float4*)&wb[lane][0] = make_float4(w[0], w[1], w[2], w[3]);
      *(float4*)&wb[lane][4] = make_float4(w[4], w[5], w[6], w[7]);
    }
    __syncthreads();
    int cend = c + n;
    for (int i = c + hw; i < cend; i += 2){
      int e = i - c;
      int4 nd = ndb[e];
      float4 wlo = *(const float4*)&wb[e][0];
      float4 whi = *(const float4*)&wb[e][4];
      float2 v0 = __half22float2(tfh[(size_t)nd.x*32 + j]);
      float2 v1 = __half22float2(tfh[(size_t)nd.y*32 + j]);
      float2 v2 = __half22float2(tfh[(size_t)nd.z*32 + j]);
      float hre = (v0.x*f0.x - v0.y*f0.y) + (v1.x*f1.x - v1.y*f1.y) + v2.x;
      float him = (v0.x*f0.y + v0.y*f0.x) + (v1.x*f1.y + v1.y*f1.x) + v2.y;
      ur[0] += wlo.x*hre; ui[0] += wlo.x*him; s[0] += wlo.x;
      ur[1] += wlo.y*hre; ui[1] += wlo.y*him; s[1] += wlo.y;
      ur[2] += wlo.z*hre; ui[2] += wlo.z*him; s[2] += wlo.z;
      ur[3] += wlo.w*hre; ui[3] += wlo.w*him; s[3] += wlo.w;
      ur[4] += whi.x*hre; ui[4] += whi.x*him; s[4] += whi.x;
      ur[5] += whi.y*hre; ui[5] += whi.y*him; s[5] += whi.y;
      ur[6] += whi.z*hre; ui[6] += whi.z*him; s[6] += whi.z;
      ur[7] += whi.w*hre; ui[7] += whi.w*him; s[7] += whi.w;
    }
    __syncthreads();
  }
  #pragma unroll
  for (int k = 0; k < 8; ++k){
    ur[k] += __shfl_xor(ur[k], 32);
    ui[k] += __shfl_xor(ui[k], 32);
    s[k]  += __shfl_xor(s[k], 32);
  }
  #pragma unroll
  for (int kk = 0; kk < 4; ++kk){
    int k = hw*4 + kk;
    float inv = 1.f / (3.f * s[k]);
    ftw[k*32 + j] = make_float2(ur[k]*inv, ui[k]*inv);
  }
}

// ---- s1: acc[p][d] = sum_g cnt[p][g] * tanh(fc1 @ elu(ft[p][g]) + b1)[d]
// dense rows (no gather). 32 rows x 128 dims per block, 128 threads, micro 8x4.
// LDS tiles in [row][k] layout, stride 34 (b64-aligned, conflict-free strided reads).
__global__ __launch_bounds__(128) void k_s1g(const float* __restrict__ ftbase,
                                             const int* __restrict__ cntt,
                                             const float* __restrict__ fc1_w,
                                             const float* __restrict__ fc1_b,
                                             float* __restrict__ acc_p){
  __shared__ float An[32][34];
  __shared__ float Bn[128][34];
  __shared__ float red[128][5];

  int bid = blockIdx.x;          // 512 blocks: p*256 + mb
  int p  = bid >> 8;
  int mb = bid & 255;
  int t = threadIdx.x;
  int tx = t & 3;                // row group: rows tx + 4i, i=0..7
  int ty = t >> 2;               // col group: cols ty + 32j, j=0..3

  const float4* ft4 = (const float4*)(ftbase + ((size_t)p*NG + (size_t)mb*32)*512);
  const float4* W4  = (const float4*)fc1_w;   // [128][128 float4]

  float acc[8][4];
  #pragma unroll
  for (int i = 0; i < 8; ++i)
    #pragma unroll
    for (int j = 0; j < 4; ++j) acc[i][j] = 0.f;

  for (int k0 = 0; k0 < 512; k0 += 32){
    // stage A: 32 rows x 8 float4 = 256, 2 per thread; elu applied
    #pragma unroll
    for (int qq = 0; qq < 2; ++qq){
      int q = t + qq*128;
      int m = q >> 3, kq = q & 7;
      float4 v = ft4[(size_t)m*128 + (k0 >> 2) + kq];
      v.x = v.x > 0.f ? v.x : expm1f(v.x);
      v.y = v.y > 0.f ? v.y : expm1f(v.y);
      v.z = v.z > 0.f ? v.z : expm1f(v.z);
      v.w = v.w > 0.f ? v.w : expm1f(v.w);
      *(float2*)&An[m][kq*4]     = make_float2(v.x, v.y);
      *(float2*)&An[m][kq*4 + 2] = make_float2(v.z, v.w);
    }
    // stage B: 128 rows x 8 float4 = 1024, 8 per thread
    #pragma unroll
    for (int qq = 0; qq < 8; ++qq){
      int q = t + qq*128;
      int d = q >> 3, kq = q & 7;
      float4 v = W4[(size_t)d*128 + (k0 >> 2) + kq];
      *(float2*)&Bn[d][kq*4]     = make_float2(v.x, v.y);
      *(float2*)&Bn[d][kq*4 + 2] = make_float2(v.z, v.w);
    }
    __syncthreads();
    #pragma unroll 4
    for (int kk2 = 0; kk2 < 16; ++kk2){
      float2 a2[8], b2[4];
      #pragma unroll
      for (int i = 0; i < 8; ++i) a2[i] = *(const float2*)&An[tx + 4*i][kk2*2];
      #pragma unroll
      for (int j = 0; j < 4; ++j) b2[j] = *(const float2*)&Bn[ty + 32*j][kk2*2];
      #pragma unroll
      for (int i = 0; i < 8; ++i)
        #pragma unroll
        for (int j = 0; j < 4; ++j)
          acc[i][j] += a2[i].x*b2[j].x + a2[i].y*b2[j].y;
    }
    __syncthreads();
  }

  // epilogue: weighted tanh column-sums
  float cf[8];
  #pragma unroll
  for (int i = 0; i < 8; ++i)
    cf[i] = (float)cntt[p*NG + mb*32 + tx + 4*i];
  float csum[4];
  #pragma unroll
  for (int j = 0; j < 4; ++j){
    float bv = fc1_b[ty + 32*j];
    float sv = 0.f;
    #pragma unroll
    for (int i = 0; i < 8; ++i)
      sv += cf[i] * tanhf(acc[i][j] + bv);
    csum[j] = sv;
  }
  #pragma unroll
  for (int j = 0; j < 4; ++j) red[ty + 32*j][tx] = csum[j];
  __syncthreads();
  if (t < 128){
    float sv = red[t][0] + red[t][1] + red[t][2] + red[t][3];
    atomicAdd(&acc_p[p*128 + t], sv);
  }
}

// ---- beta softmax over 2 metapaths ----
__global__ void k_beta(const float* __restrict__ acc, const float* __restrict__ fc2_w,
                       float* __restrict__ beta){
  int t = threadIdx.x;  // 64
  float s0 = acc[t]*fc2_w[t] + acc[t+64]*fc2_w[t+64];
  float s1 = acc[128+t]*fc2_w[t] + acc[192+t]*fc2_w[t+64];
  #pragma unroll
  for (int mask = 1; mask < 64; mask <<= 1){
    s0 += __shfl_xor(s0, mask, 64);
    s1 += __shfl_xor(s1, mask, 64);
  }
  if (t == 0){
    float z0 = s0 / (float)NB, z1 = s1 / (float)NB;
    float mz = fmaxf(z0, z1);
    float e0 = expf(z0 - mz), e1 = expf(z1 - mz);
    float inv = 1.f / (e0 + e1);
    beta[0] = e0*inv; beta[1] = e1*inv;
  }
}

// ---- hagg + logits (gather + elu fused) ----
__global__ void k_final(const float* __restrict__ ft0, const float* __restrict__ ft1,
                        const int* __restrict__ tgt0, const int* __restrict__ tgt1,
                        const float* __restrict__ beta, const float* __restrict__ fc_w,
                        const float* __restrict__ fc_b, float* __restrict__ d_out){
  __shared__ float lds[512];
  int b = blockIdx.x, t = threadIdx.x;  // 512 threads
  float b0 = beta[0], b1 = beta[1];
  int g0 = tgt0[b], g1 = tgt1[b];
  float v0 = ft0[(size_t)g0*512 + t]; v0 = v0 > 0.f ? v0 : expm1f(v0);
  float v1 = ft1[(size_t)g1*512 + t]; v1 = v1 > 0.f ? v1 : expm1f(v1);
  float h = b0*v0 + b1*v1;
  lds[t] = h;
  d_out[(size_t)NB*OUTD + (size_t)b*512 + t] = h;
  __syncthreads();
  int o = t >> 5, j = t & 31;
  float s = 0.f;
  const float* w = fc_w + o*512;
  for (int d = j; d < 512; d += 32) s += lds[d]*w[d];
  #pragma unroll
  for (int mask = 1; mask < 32; mask <<= 1) s += __shfl_xor(s, mask, 32);
  if (j == 0) d_out[(size_t)b*OUTD + o] = s + fc_b[o];
}

extern "C" void kernel_launch(void* const* d_in, const int* in_sizes, int n_in,
                              void* d_out, int out_size, void* d_ws, size_t ws_size,
                              hipStream_t stream){
  const float* feat0  = (const float*)d_in[0];
  const float* feat1  = (const float*)d_in[1];
  const float* W0     = (const float*)d_in[2];
  const float* b0     = (const float*)d_in[3];
  const float* W1     = (const float*)d_in[4];
  const float* b1     = (const float*)d_in[5];
  const float* r_vec  = (const float*)d_in[6];
  const float* attn0  = (const float*)d_in[7];
  const float* attn1  = (const float*)d_in[8];
  const float* fc1_w  = (const float*)d_in[9];
  const float* fc1_b  = (const float*)d_in[10];
  const float* fc2_w  = (const float*)d_in[11];
  const float* fc_w   = (const float*)d_in[12];
  const float* fc_b   = (const float*)d_in[13];
  const int*   idx0   = (const int*)d_in[14];
  const int*   idx1   = (const int*)d_in[15];
  const int*   mpi0   = (const int*)d_in[16];
  const int*   mdst0  = (const int*)d_in[17];
  const int*   mtgt0  = (const int*)d_in[18];
  const int*   mpi1   = (const int*)d_in[19];
  const int*   mdst1  = (const int*)d_in[20];
  const int*   mtgt1  = (const int*)d_in[21];

  float* ws      = (float*)d_ws;
  __half* tf16   = (__half*)(ws + OFF_TF16);
  float* finals  = ws + OFF_FINALS;
  float* Amat    = ws + OFF_A;
  float* acc     = ws + OFF_ACC;
  float* beta    = ws + OFF_BETA;
  __half* P      = (__half*)(ws + OFF_P);
  int4*  sorted  = (int4*)(ws + OFF_SORTED);
  int*   counts  = (int*)(ws + OFF_COUNTS);
  int*   cntt    = (int*)(ws + OFF_CNTT);
  int*   curs    = (int*)(ws + OFF_CURS);
  int*   offs    = (int*)(ws + OFF_OFFS);
  float* ftb     = ws + OFF_FT;
  float* ft0     = ftb;
  float* ft1     = ftb + (size_t)NG*512;

  k_prep<<<1, 256, 0, stream>>>(r_vec, attn0, attn1, finals, Amat, acc, beta);
  k_zeroi<<<128, 256, 0, stream>>>(counts, 4*NG);   // counts + cntt (contiguous)
  k_hist3<<<(2*NE + 2*NB + 255)/256, 256, 0, stream>>>(mdst0, mdst1, mtgt0, mtgt1,
                                                       counts, cntt);
  k_scan<<<1, 1024, 0, stream>>>(counts, offs, curs);
  k_scatter2<<<(2*NE + 255)/256, 256, 0, stream>>>(mpi0, mdst0, mpi1, mdst1,
                                                   offs, curs, sorted);

  k_transform2<<<(NT0 + 63)/64 + (NT1 + 63)/64, 256, 0, stream>>>(
      feat0, W0, b0, idx0, feat1, W1, b1, idx1, tf16);
  k_pmat<<<(NNODES + 63)/64, 256, 0, stream>>>(tf16, Amat, P);

  k_seg<<<2*NG, 64, 0, stream>>>(tf16, P, sorted, offs, finals, ftb);

  k_s1g<<<512, 128, 0, stream>>>(ftb, cntt, fc1_w, fc1_b, acc);
  k_beta<<<1, 64, 0, stream>>>(acc, fc2_w, beta);
  k_final<<<NB, 512, 0, stream>>>(ft0, ft1, mtgt0, mtgt1, beta, fc_w, fc_b,
                                  (float*)d_out);
}

// Round 8
// 294.259 us; speedup vs baseline: 1.1104x; 1.1104x over previous
//
#include <hip/hip_runtime.h>
#include <hip/hip_fp16.h>
#include <math.h>

#define NNODES 100000
#define NT0 60000
#define NT1 40000
#define FD0 128
#define FD1 64
#define HID 64
#define HEADS 8
#define OUTD 16
#define AVEC 128
#define NE 250000
#define NG 8192
#define NB 8192

// workspace layout (float offsets)
#define OFF_TF16    0ull          // 100000*64 halves = 3,200,000 floats
#define OFF_FINALS  3200000ull    // 512
#define OFF_A       3200512ull    // 3,072
#define OFF_ACC     3203584ull    // 256
#define OFF_BETA    3203840ull    // 256
#define OFF_P       3204096ull    // 2,400,000 floats = 4,800,000 halves
#define OFF_SORTED  5604096ull    // 2,000,000 (500,000 int4)
#define OFF_COUNTS  7604096ull    // 16,384 ints (dst histograms, both p)
#define OFF_CNTT    7620480ull    // 16,384 ints (tgt histograms, both p)
#define OFF_CURS    7636864ull    // 16,384 ints
#define OFF_OFFS    7653248ull    // 16,640 ints (16,385 used)
#define OFF_FT      7669888ull    // 2*NG*512 = 8,388,608
// total = 16,058,496 floats = 64.2 MB

// ---- prep: finals + logit-projection matrices A, zero acc ----
__global__ __launch_bounds__(256) void k_prep(const float* __restrict__ r_vec,
                       const float* __restrict__ attn0, const float* __restrict__ attn1,
                       float* __restrict__ finals, float* __restrict__ A,
                       float* __restrict__ acc, float* __restrict__ beta){
  __shared__ float2 fl[192];   // [pi][pair]
  int t = threadIdx.x;
  if (t < 32){
    int j = t;
    const float2* rv = (const float2*)r_vec;
    float2 r0 = rv[j];
    float2 r1 = rv[32 + j];
    float n0 = rsqrtf(r0.x*r0.x + r0.y*r0.y);
    float n1 = rsqrtf(r1.x*r1.x + r1.y*r1.y);
    r0.x *= n0; r0.y *= n0; r1.x *= n1; r1.y *= n1;
    float2 rf1 = make_float2(r0.x, -r0.y);   // conj(r0)
    float2 rf3 = make_float2(r1.x, -r1.y);   // conj(r1)
    float2 F00 = make_float2(rf1.x*r0.x - rf1.y*r0.y, rf1.x*r0.y + rf1.y*r0.x);
    float2 F10 = make_float2(rf3.x*r1.x - rf3.y*r1.y, rf3.x*r1.y + rf3.y*r1.x);
    float2 one = make_float2(1.f, 0.f);
    float2* F = (float2*)finals;
    F[0*32+j] = F00; F[1*32+j] = rf1; F[2*32+j] = one;
    F[3*32+j] = F10; F[4*32+j] = rf3; F[5*32+j] = one;
    fl[0*32+j] = F00; fl[1*32+j] = rf1; fl[2*32+j] = one;
    fl[3*32+j] = F10; fl[4*32+j] = rf3; fl[5*32+j] = one;
  }
  __syncthreads();
  for (int idx = t; idx < 1536; idx += 256){
    int pair = idx & 31, k = (idx >> 5) & 7, pi = idx >> 8;   // pi 0..5
    const float* at = (pi >= 3) ? attn1 : attn0;
    float2 f = fl[pi*32 + pair];
    float a0 = at[k*64 + 2*pair], a1 = at[k*64 + 2*pair + 1];
    A[(pi*8+k)*64 + 2*pair]     = (f.x*a0 + f.y*a1) * (1.f/3.f);
    A[(pi*8+k)*64 + 2*pair + 1] = (f.x*a1 - f.y*a0) * (1.f/3.f);
  }
  acc[t] = 0.f;
  if (t < 2) beta[t] = 0.f;
}

// ---- merged per-type linear: tf16[idx[m]] = f16(feat[m] @ W.T + b) ----
// dot-product style: A and B staged [row][k] at stride 34, f2 LDS ops.
// 64 nodes x 64 dims per block, 256 threads, micro 4x4
// rows tx+16i (tx=t&15), cols ty*4+j (ty=t>>4)
__global__ __launch_bounds__(256) void k_transform2(const float* __restrict__ feat0,
                  const float* __restrict__ W0v, const float* __restrict__ b0v,
                  const int* __restrict__ idx0,
                  const float* __restrict__ feat1, const float* __restrict__ W1v,
                  const float* __restrict__ b1v, const int* __restrict__ idx1,
                  __half* __restrict__ tf16){
  __shared__ float An[64][34];
  __shared__ float Bn[64][34];
  const int nb0 = (NT0 + 63)/64;
  int bid = blockIdx.x;
  const float *feat, *W, *bias; const int* idx; int n_nodes, F, m0;
  if (bid < nb0){ feat=feat0; W=W0v; bias=b0v; idx=idx0; n_nodes=NT0; F=FD0; m0=bid*64; }
  else { feat=feat1; W=W1v; bias=b1v; idx=idx1; n_nodes=NT1; F=FD1; m0=(bid-nb0)*64; }
  int t = threadIdx.x;
  int tx = t & 15;
  int ty = t >> 4;
  int Fq = F >> 2;

  float acc[4][4];
  #pragma unroll
  for (int i = 0; i < 4; ++i)
    #pragma unroll
    for (int j = 0; j < 4; ++j) acc[i][j] = 0.f;

  const float4* feat4 = (const float4*)feat;
  const float4* W4 = (const float4*)W;

  for (int k0 = 0; k0 < F; k0 += 32){
    // stage A: 64 rows x 8 float4 = 512, 2 per thread, natural [row][k]
    #pragma unroll
    for (int qq = 0; qq < 2; ++qq){
      int q = t + qq*256;
      int m = q >> 3, kq = q & 7;
      int gm = m0 + m; if (gm > n_nodes - 1) gm = n_nodes - 1;
      float4 v = feat4[(size_t)gm*Fq + (k0 >> 2) + kq];
      *(float2*)&An[m][kq*4]     = make_float2(v.x, v.y);
      *(float2*)&An[m][kq*4 + 2] = make_float2(v.z, v.w);
    }
    // stage B: 64 dim-rows x 8 float4 = 512, 2 per thread
    #pragma unroll
    for (int qq = 0; qq < 2; ++qq){
      int q = t + qq*256;
      int d = q >> 3, kq = q & 7;
      float4 v = W4[(size_t)d*Fq + (k0 >> 2) + kq];
      *(float2*)&Bn[d][kq*4]     = make_float2(v.x, v.y);
      *(float2*)&Bn[d][kq*4 + 2] = make_float2(v.z, v.w);
    }
    __syncthreads();
    #pragma unroll 8
    for (int kk2 = 0; kk2 < 16; ++kk2){
      float2 a2[4], b2[4];
      #pragma unroll
      for (int i = 0; i < 4; ++i) a2[i] = *(const float2*)&An[tx + 16*i][kk2*2];
      #pragma unroll
      for (int j = 0; j < 4; ++j) b2[j] = *(const float2*)&Bn[ty*4 + j][kk2*2];
      #pragma unroll
      for (int i = 0; i < 4; ++i)
        #pragma unroll
        for (int j = 0; j < 4; ++j)
          acc[i][j] += a2[i].x*b2[j].x + a2[i].y*b2[j].y;
    }
    __syncthreads();
  }

  float4 bv = *(const float4*)&bias[ty*4];
  #pragma unroll
  for (int i = 0; i < 4; ++i){
    int gm = m0 + tx + 16*i;
    if (gm < n_nodes){
      union { __half2 h2[2]; uint2 u; } pk;
      pk.h2[0] = __floats2half2_rn(acc[i][0] + bv.x, acc[i][1] + bv.y);
      pk.h2[1] = __floats2half2_rn(acc[i][2] + bv.z, acc[i][3] + bv.w);
      *(uint2*)&tf16[(size_t)idx[gm]*HID + ty*4] = pk.u;
    }
  }
}

// ---- P = tf16 @ A.T per metapath/position, stored f16 ----
__global__ __launch_bounds__(256) void k_pmat(const __half* __restrict__ tf16,
                                              const float* __restrict__ A,
                                              __half* __restrict__ P){
  __shared__ float tfl[64][65];
  __shared__ float Al[48][65];
  int t = threadIdx.x;
  int n0 = blockIdx.x * 64;
  for (int q = t; q < 3072; q += 256) Al[q >> 6][q & 63] = A[q];
  const __half2* tfh = (const __half2*)(tf16 + (size_t)n0*64);
  for (int q = t; q < 2048; q += 256){
    int n = q >> 5, dq = q & 31;
    float2 v = make_float2(0.f, 0.f);
    if (n0 + n < NNODES) v = __half22float2(tfh[n*32 + dq]);
    tfl[n][dq*2] = v.x; tfl[n][dq*2+1] = v.y;
  }
  __syncthreads();
  int nl = t >> 2, q = t & 3;
  float s[12];
  #pragma unroll
  for (int c = 0; c < 12; ++c) s[c] = 0.f;
  #pragma unroll 4
  for (int d = 0; d < 64; ++d){
    float tv = tfl[nl][d];
    #pragma unroll
    for (int c = 0; c < 12; ++c) s[c] += tv * Al[q*12 + c][d];
  }
  int gn = n0 + nl;
  if (gn < NNODES){
    #pragma unroll
    for (int c = 0; c < 12; ++c){
      int cg = q*12 + c;
      int p = cg >= 24;
      int w = cg - p*24;
      P[(size_t)p*2400000 + (size_t)gn*24 + w] = __float2half(s[c]);
    }
  }
}

// ---- zero int buffer ----
__global__ void k_zeroi(int* __restrict__ p, int n){
  int t = blockIdx.x*blockDim.x + threadIdx.x;
  if (t < n) p[t] = 0;
}

// ---- histograms: dst (both p) + tgt (both p) ----
__global__ void k_hist3(const int* __restrict__ d0, const int* __restrict__ d1,
                        const int* __restrict__ t0, const int* __restrict__ t1,
                        int* __restrict__ counts, int* __restrict__ cntt){
  int e = blockIdx.x*blockDim.x + threadIdx.x;
  if (e < NE) atomicAdd(&counts[d0[e]], 1);
  else if (e < 2*NE) atomicAdd(&counts[NG + d1[e-NE]], 1);
  else if (e < 2*NE + NB) atomicAdd(&cntt[t0[e-2*NE]], 1);
  else if (e < 2*NE + 2*NB) atomicAdd(&cntt[NG + t1[e-2*NE-NB]], 1);
}

// ---- exclusive scan over 16384 counts; also zero cursors ----
__global__ __launch_bounds__(1024) void k_scan(const int* __restrict__ counts,
                                               int* __restrict__ offs,
                                               int* __restrict__ curs){
  __shared__ int lds[1024];
  int t = threadIdx.x;
  int base = t*16;
  int v[16]; int sum = 0;
  #pragma unroll
  for (int i = 0; i < 16; ++i){ v[i] = counts[base+i]; sum += v[i]; }
  lds[t] = sum;
  __syncthreads();
  for (int off = 1; off < 1024; off <<= 1){
    int x = (t >= off) ? lds[t-off] : 0;
    __syncthreads();
    lds[t] += x;
    __syncthreads();
  }
  int excl = lds[t] - sum;
  #pragma unroll
  for (int i = 0; i < 16; ++i){ offs[base+i] = excl; excl += v[i]; curs[base+i] = 0; }
  if (t == 1023) offs[2*NG] = excl;
}

// ---- scatter both metapaths' edges into dst-sorted order ----
__global__ void k_scatter2(const int* __restrict__ m0, const int* __restrict__ d0,
                           const int* __restrict__ m1, const int* __restrict__ d1,
                           const int* __restrict__ offs, int* __restrict__ curs,
                           int4* __restrict__ sorted){
  int e = blockIdx.x*blockDim.x + threadIdx.x;
  if (e >= 2*NE) return;
  const int* mp; int d;
  if (e < NE){ mp = m0 + (size_t)e*3; d = d0[e]; }
  else { mp = m1 + (size_t)(e-NE)*3; d = NG + d1[e-NE]; }
  int pos = offs[d] + atomicAdd(&curs[d], 1);
  sorted[pos] = make_int4(mp[0], mp[1], mp[2], 0);
}

// ---- fused per-segment softmax-agg, both metapaths in one grid ----
__global__ __launch_bounds__(64) void k_seg(const __half* __restrict__ tf16,
                                            const __half* __restrict__ P,
                                            const int4* __restrict__ sorted,
                                            const int* __restrict__ offs,
                                            const float* __restrict__ finals,
                                            float* __restrict__ ft){
  int bid = blockIdx.x;
  int p = bid >> 13;
  int lane = threadIdx.x;
  int hw = lane >> 5, j = lane & 31;
  int start = offs[bid], end = offs[bid+1];
  float2* ftw = (float2*)(ft + (size_t)bid*512);
  if (start == end){
    #pragma unroll
    for (int kk = 0; kk < 4; ++kk) ftw[(hw*4+kk)*32 + j] = make_float2(0.f, 0.f);
    return;
  }
  const float2* F2 = (const float2*)(finals + p*192);
  float2 f0 = F2[j], f1 = F2[32 + j];
  const __half2* tfh = (const __half2*)tf16;
  const __half* Pp = P + (size_t)p*2400000;

  __shared__ int4 ndb[64];
  __shared__ float wb[64][8];

  float s[8], ur[8], ui[8];
  #pragma unroll
  for (int k = 0; k < 8; ++k){ s[k] = 0.f; ur[k] = 0.f; ui[k] = 0.f; }

  for (int c = start; c < end; c += 64){
    int n = end - c; if (n > 64) n = 64;
    if (lane < n){
      int4 nd = sorted[c + lane];
      ndb[lane] = nd;
      float4 rA = *(const float4*)(Pp + (size_t)nd.x*24);
      float4 rB = *(const float4*)(Pp + (size_t)nd.y*24 + 8);
      float4 rC = *(const float4*)(Pp + (size_t)nd.z*24 + 16);
      const __half2* ha = (const __half2*)&rA;
      const __half2* hb = (const __half2*)&rB;
      const __half2* hc = (const __half2*)&rC;
      float w[8];
      #pragma unroll
      for (int m = 0; m < 4; ++m){
        float2 va = __half22float2(ha[m]);
        float2 vb = __half22float2(hb[m]);
        float2 vc = __half22float2(hc[m]);
        float x0 = va.x + vb.x + vc.x;
        float x1 = va.y + vb.y + vc.y;
        x0 = x0 > 0.f ? x0 : 0.01f*x0;
        x1 = x1 > 0.f ? x1 : 0.01f*x1;
        w[2*m]   = __expf(x0);
        w[2*m+1] = __expf(x1);
      }
      *(float4*)&wb[lane][0] = make_float4(w[0], w[1], w[2], w[3]);
      *(float4*)&wb[lane][4] = make_float4(w[4], w[5], w[6], w[7]);
    }
    __syncthreads();
    int cend = c + n;
    for (int i = c + hw; i < cend; i += 2){
      int e = i - c;
      int4 nd = ndb[e];
      float4 wlo = *(const float4*)&wb[e][0];
      float4 whi = *(const float4*)&wb[e][4];
      float2 v0 = __half22float2(tfh[(size_t)nd.x*32 + j]);
      float2 v1 = __half22float2(tfh[(size_t)nd.y*32 + j]);
      float2 v2 = __half22float2(tfh[(size_t)nd.z*32 + j]);
      float hre = (v0.x*f0.x - v0.y*f0.y) + (v1.x*f1.x - v1.y*f1.y) + v2.x;
      float him = (v0.x*f0.y + v0.y*f0.x) + (v1.x*f1.y + v1.y*f1.x) + v2.y;
      ur[0] += wlo.x*hre; ui[0] += wlo.x*him; s[0] += wlo.x;
      ur[1] += wlo.y*hre; ui[1] += wlo.y*him; s[1] += wlo.y;
      ur[2] += wlo.z*hre; ui[2] += wlo.z*him; s[2] += wlo.z;
      ur[3] += wlo.w*hre; ui[3] += wlo.w*him; s[3] += wlo.w;
      ur[4] += whi.x*hre; ui[4] += whi.x*him; s[4] += whi.x;
      ur[5] += whi.y*hre; ui[5] += whi.y*him; s[5] += whi.y;
      ur[6] += whi.z*hre; ui[6] += whi.z*him; s[6] += whi.z;
      ur[7] += whi.w*hre; ui[7] += whi.w*him; s[7] += whi.w;
    }
    __syncthreads();
  }
  #pragma unroll
  for (int k = 0; k < 8; ++k){
    ur[k] += __shfl_xor(ur[k], 32);
    ui[k] += __shfl_xor(ui[k], 32);
    s[k]  += __shfl_xor(s[k], 32);
  }
  #pragma unroll
  for (int kk = 0; kk < 4; ++kk){
    int k = hw*4 + kk;
    float inv = 1.f / (3.f * s[k]);
    ftw[k*32 + j] = make_float2(ur[k]*inv, ui[k]*inv);
  }
}

// ---- s1: acc[p][d] = sum_g cnt[p][g] * tanh(fc1 @ elu(ft[p][g]) + b1)[d]
// 32 rows x 128 dims per block, 256 threads (4 waves), micro 4x4.
// rows tx+8i (tx=t&7), cols ty*4+j (ty=t>>3). stride-34 f2 LDS (proven ~0 conflicts).
__global__ __launch_bounds__(256) void k_s1g(const float* __restrict__ ftbase,
                                             const int* __restrict__ cntt,
                                             const float* __restrict__ fc1_w,
                                             const float* __restrict__ fc1_b,
                                             float* __restrict__ acc_p){
  __shared__ float An[32][34];
  __shared__ float Bn[128][34];
  __shared__ float red[128][9];

  int bid = blockIdx.x;          // 512 blocks: p*256 + mb
  int p  = bid >> 8;
  int mb = bid & 255;
  int t = threadIdx.x;
  int tx = t & 7;                // rows tx + 8i, i=0..3
  int ty = t >> 3;               // cols ty*4 + j, j=0..3

  const float4* ft4 = (const float4*)(ftbase + ((size_t)p*NG + (size_t)mb*32)*512);
  const float4* W4  = (const float4*)fc1_w;   // [128][128 float4]

  float acc[4][4];
  #pragma unroll
  for (int i = 0; i < 4; ++i)
    #pragma unroll
    for (int j = 0; j < 4; ++j) acc[i][j] = 0.f;

  for (int k0 = 0; k0 < 512; k0 += 32){
    // stage A: 32 rows x 8 float4 = 256, 1 per thread; elu applied
    {
      int m = t >> 3, kq = t & 7;
      float4 v = ft4[(size_t)m*128 + (k0 >> 2) + kq];
      v.x = v.x > 0.f ? v.x : expm1f(v.x);
      v.y = v.y > 0.f ? v.y : expm1f(v.y);
      v.z = v.z > 0.f ? v.z : expm1f(v.z);
      v.w = v.w > 0.f ? v.w : expm1f(v.w);
      *(float2*)&An[m][kq*4]     = make_float2(v.x, v.y);
      *(float2*)&An[m][kq*4 + 2] = make_float2(v.z, v.w);
    }
    // stage B: 128 rows x 8 float4 = 1024, 4 per thread
    #pragma unroll
    for (int qq = 0; qq < 4; ++qq){
      int q = t + qq*256;
      int d = q >> 3, kq = q & 7;
      float4 v = W4[(size_t)d*128 + (k0 >> 2) + kq];
      *(float2*)&Bn[d][kq*4]     = make_float2(v.x, v.y);
      *(float2*)&Bn[d][kq*4 + 2] = make_float2(v.z, v.w);
    }
    __syncthreads();
    #pragma unroll 8
    for (int kk2 = 0; kk2 < 16; ++kk2){
      float2 a2[4], b2[4];
      #pragma unroll
      for (int i = 0; i < 4; ++i) a2[i] = *(const float2*)&An[tx + 8*i][kk2*2];
      #pragma unroll
      for (int j = 0; j < 4; ++j) b2[j] = *(const float2*)&Bn[ty*4 + j][kk2*2];
      #pragma unroll
      for (int i = 0; i < 4; ++i)
        #pragma unroll
        for (int j = 0; j < 4; ++j)
          acc[i][j] += a2[i].x*b2[j].x + a2[i].y*b2[j].y;
    }
    __syncthreads();
  }

  // epilogue: weighted tanh column-sums
  float cf[4];
  #pragma unroll
  for (int i = 0; i < 4; ++i)
    cf[i] = (float)cntt[p*NG + mb*32 + tx + 8*i];
  #pragma unroll
  for (int j = 0; j < 4; ++j){
    float bv = fc1_b[ty*4 + j];
    float sv = 0.f;
    #pragma unroll
    for (int i = 0; i < 4; ++i)
      sv += cf[i] * tanhf(acc[i][j] + bv);
    red[ty*4 + j][tx] = sv;
  }
  __syncthreads();
  if (t < 128){
    float sv = 0.f;
    #pragma unroll
    for (int x = 0; x < 8; ++x) sv += red[t][x];
    atomicAdd(&acc_p[p*128 + t], sv);
  }
}

// ---- beta softmax over 2 metapaths ----
__global__ void k_beta(const float* __restrict__ acc, const float* __restrict__ fc2_w,
                       float* __restrict__ beta){
  int t = threadIdx.x;  // 64
  float s0 = acc[t]*fc2_w[t] + acc[t+64]*fc2_w[t+64];
  float s1 = acc[128+t]*fc2_w[t] + acc[192+t]*fc2_w[t+64];
  #pragma unroll
  for (int mask = 1; mask < 64; mask <<= 1){
    s0 += __shfl_xor(s0, mask, 64);
    s1 += __shfl_xor(s1, mask, 64);
  }
  if (t == 0){
    float z0 = s0 / (float)NB, z1 = s1 / (float)NB;
    float mz = fmaxf(z0, z1);
    float e0 = expf(z0 - mz), e1 = expf(z1 - mz);
    float inv = 1.f / (e0 + e1);
    beta[0] = e0*inv; beta[1] = e1*inv;
  }
}

// ---- hagg + logits (gather + elu fused) ----
__global__ void k_final(const float* __restrict__ ft0, const float* __restrict__ ft1,
                        const int* __restrict__ tgt0, const int* __restrict__ tgt1,
                        const float* __restrict__ beta, const float* __restrict__ fc_w,
                        const float* __restrict__ fc_b, float* __restrict__ d_out){
  __shared__ float lds[512];
  int b = blockIdx.x, t = threadIdx.x;  // 512 threads
  float b0 = beta[0], b1 = beta[1];
  int g0 = tgt0[b], g1 = tgt1[b];
  float v0 = ft0[(size_t)g0*512 + t]; v0 = v0 > 0.f ? v0 : expm1f(v0);
  float v1 = ft1[(size_t)g1*512 + t]; v1 = v1 > 0.f ? v1 : expm1f(v1);
  float h = b0*v0 + b1*v1;
  lds[t] = h;
  d_out[(size_t)NB*OUTD + (size_t)b*512 + t] = h;
  __syncthreads();
  int o = t >> 5, j = t & 31;
  float s = 0.f;
  const float* w = fc_w + o*512;
  for (int d = j; d < 512; d += 32) s += lds[d]*w[d];
  #pragma unroll
  for (int mask = 1; mask < 32; mask <<= 1) s += __shfl_xor(s, mask, 32);
  if (j == 0) d_out[(size_t)b*OUTD + o] = s + fc_b[o];
}

extern "C" void kernel_launch(void* const* d_in, const int* in_sizes, int n_in,
                              void* d_out, int out_size, void* d_ws, size_t ws_size,
                              hipStream_t stream){
  const float* feat0  = (const float*)d_in[0];
  const float* feat1  = (const float*)d_in[1];
  const float* W0     = (const float*)d_in[2];
  const float* b0     = (const float*)d_in[3];
  const float* W1     = (const float*)d_in[4];
  const float* b1     = (const float*)d_in[5];
  const float* r_vec  = (const float*)d_in[6];
  const float* attn0  = (const float*)d_in[7];
  const float* attn1  = (const float*)d_in[8];
  const float* fc1_w  = (const float*)d_in[9];
  const float* fc1_b  = (const float*)d_in[10];
  const float* fc2_w  = (const float*)d_in[11];
  const float* fc_w   = (const float*)d_in[12];
  const float* fc_b   = (const float*)d_in[13];
  const int*   idx0   = (const int*)d_in[14];
  const int*   idx1   = (const int*)d_in[15];
  const int*   mpi0   = (const int*)d_in[16];
  const int*   mdst0  = (const int*)d_in[17];
  const int*   mtgt0  = (const int*)d_in[18];
  const int*   mpi1   = (const int*)d_in[19];
  const int*   mdst1  = (const int*)d_in[20];
  const int*   mtgt1  = (const int*)d_in[21];

  float* ws      = (float*)d_ws;
  __half* tf16   = (__half*)(ws + OFF_TF16);
  float* finals  = ws + OFF_FINALS;
  float* Amat    = ws + OFF_A;
  float* acc     = ws + OFF_ACC;
  float* beta    = ws + OFF_BETA;
  __half* P      = (__half*)(ws + OFF_P);
  int4*  sorted  = (int4*)(ws + OFF_SORTED);
  int*   counts  = (int*)(ws + OFF_COUNTS);
  int*   cntt    = (int*)(ws + OFF_CNTT);
  int*   curs    = (int*)(ws + OFF_CURS);
  int*   offs    = (int*)(ws + OFF_OFFS);
  float* ftb     = ws + OFF_FT;
  float* ft0     = ftb;
  float* ft1     = ftb + (size_t)NG*512;

  k_prep<<<1, 256, 0, stream>>>(r_vec, attn0, attn1, finals, Amat, acc, beta);
  k_zeroi<<<128, 256, 0, stream>>>(counts, 4*NG);   // counts + cntt (contiguous)
  k_hist3<<<(2*NE + 2*NB + 255)/256, 256, 0, stream>>>(mdst0, mdst1, mtgt0, mtgt1,
                                                       counts, cntt);
  k_scan<<<1, 1024, 0, stream>>>(counts, offs, curs);
  k_scatter2<<<(2*NE + 255)/256, 256, 0, stream>>>(mpi0, mdst0, mpi1, mdst1,
                                                   offs, curs, sorted);

  k_transform2<<<(NT0 + 63)/64 + (NT1 + 63)/64, 256, 0, stream>>>(
      feat0, W0, b0, idx0, feat1, W1, b1, idx1, tf16);
  k_pmat<<<(NNODES + 63)/64, 256, 0, stream>>>(tf16, Amat, P);

  k_seg<<<2*NG, 64, 0, stream>>>(tf16, P, sorted, offs, finals, ftb);

  k_s1g<<<512, 256, 0, stream>>>(ftb, cntt, fc1_w, fc1_b, acc);
  k_beta<<<1, 64, 0, stream>>>(acc, fc2_w, beta);
  k_final<<<NB, 512, 0, stream>>>(ft0, ft1, mtgt0, mtgt1, beta, fc_w, fc_b,
                                  (float*)d_out);
}

// Round 9
// 254.949 us; speedup vs baseline: 1.2816x; 1.1542x over previous
//
#include <hip/hip_runtime.h>
#include <hip/hip_fp16.h>
#include <math.h>

#define NNODES 100000
#define NT0 60000
#define NT1 40000
#define FD0 128
#define FD1 64
#define HID 64
#define HEADS 8
#define OUTD 16
#define AVEC 128
#define NE 250000
#define NG 8192
#define NB 8192

typedef _Float16 half8v __attribute__((ext_vector_type(8)));
typedef float f32x4 __attribute__((ext_vector_type(4)));

// workspace layout (float offsets)
#define OFF_TF16    0ull          // 100000*64 halves = 3,200,000 floats
#define OFF_FINALS  3200000ull    // 512
#define OFF_A       3200512ull    // 3,072
#define OFF_ACC     3203584ull    // 256
#define OFF_BETA    3203840ull    // 256
#define OFF_FC1H    3204096ull    // 128*512 halves = 32,768 floats
#define OFF_P       3236864ull    // 2,400,000 floats = 4,800,000 halves
#define OFF_SORTED  5636864ull    // 2,000,000 (500,000 int4; byte off % 16 == 0)
#define OFF_COUNTS  7636864ull    // 16,384 ints
#define OFF_CNTT    7653248ull    // 16,384 ints (contiguous with COUNTS)
#define OFF_CURS    7669632ull    // 16,384 ints
#define OFF_OFFS    7686016ull    // 16,640 ints (16,385 used)
#define OFF_FT16    7702656ull    // 2*NG*512 halves = 4,194,304 floats
// total = 11,896,960 floats = 47.6 MB

// ---- prep: finals + logit-projection matrices A, zero acc ----
__global__ __launch_bounds__(256) void k_prep(const float* __restrict__ r_vec,
                       const float* __restrict__ attn0, const float* __restrict__ attn1,
                       float* __restrict__ finals, float* __restrict__ A,
                       float* __restrict__ acc, float* __restrict__ beta){
  __shared__ float2 fl[192];   // [pi][pair]
  int t = threadIdx.x;
  if (t < 32){
    int j = t;
    const float2* rv = (const float2*)r_vec;
    float2 r0 = rv[j];
    float2 r1 = rv[32 + j];
    float n0 = rsqrtf(r0.x*r0.x + r0.y*r0.y);
    float n1 = rsqrtf(r1.x*r1.x + r1.y*r1.y);
    r0.x *= n0; r0.y *= n0; r1.x *= n1; r1.y *= n1;
    float2 rf1 = make_float2(r0.x, -r0.y);   // conj(r0)
    float2 rf3 = make_float2(r1.x, -r1.y);   // conj(r1)
    float2 F00 = make_float2(rf1.x*r0.x - rf1.y*r0.y, rf1.x*r0.y + rf1.y*r0.x);
    float2 F10 = make_float2(rf3.x*r1.x - rf3.y*r1.y, rf3.x*r1.y + rf3.y*r1.x);
    float2 one = make_float2(1.f, 0.f);
    float2* F = (float2*)finals;
    F[0*32+j] = F00; F[1*32+j] = rf1; F[2*32+j] = one;
    F[3*32+j] = F10; F[4*32+j] = rf3; F[5*32+j] = one;
    fl[0*32+j] = F00; fl[1*32+j] = rf1; fl[2*32+j] = one;
    fl[3*32+j] = F10; fl[4*32+j] = rf3; fl[5*32+j] = one;
  }
  __syncthreads();
  for (int idx = t; idx < 1536; idx += 256){
    int pair = idx & 31, k = (idx >> 5) & 7, pi = idx >> 8;   // pi 0..5
    const float* at = (pi >= 3) ? attn1 : attn0;
    float2 f = fl[pi*32 + pair];
    float a0 = at[k*64 + 2*pair], a1 = at[k*64 + 2*pair + 1];
    A[(pi*8+k)*64 + 2*pair]     = (f.x*a0 + f.y*a1) * (1.f/3.f);
    A[(pi*8+k)*64 + 2*pair + 1] = (f.x*a1 - f.y*a0) * (1.f/3.f);
  }
  acc[t] = 0.f;
  if (t < 2) beta[t] = 0.f;
}

// ---- fc1_w -> f16 (layout [col d][k], row-major, same as input) ----
__global__ void k_cvtw(const float* __restrict__ fc1_w, __half* __restrict__ fc1h){
  int t = blockIdx.x*blockDim.x + threadIdx.x;   // 65536 threads
  fc1h[t] = __float2half(fc1_w[t]);
}

// ---- merged per-type linear: tf16[idx[m]] = f16(feat[m] @ W.T + b) ----
__global__ __launch_bounds__(256) void k_transform2(const float* __restrict__ feat0,
                  const float* __restrict__ W0v, const float* __restrict__ b0v,
                  const int* __restrict__ idx0,
                  const float* __restrict__ feat1, const float* __restrict__ W1v,
                  const float* __restrict__ b1v, const int* __restrict__ idx1,
                  __half* __restrict__ tf16){
  __shared__ float An[64][34];
  __shared__ float Bn[64][34];
  const int nb0 = (NT0 + 63)/64;
  int bid = blockIdx.x;
  const float *feat, *W, *bias; const int* idx; int n_nodes, F, m0;
  if (bid < nb0){ feat=feat0; W=W0v; bias=b0v; idx=idx0; n_nodes=NT0; F=FD0; m0=bid*64; }
  else { feat=feat1; W=W1v; bias=b1v; idx=idx1; n_nodes=NT1; F=FD1; m0=(bid-nb0)*64; }
  int t = threadIdx.x;
  int tx = t & 15;
  int ty = t >> 4;
  int Fq = F >> 2;

  float acc[4][4];
  #pragma unroll
  for (int i = 0; i < 4; ++i)
    #pragma unroll
    for (int j = 0; j < 4; ++j) acc[i][j] = 0.f;

  const float4* feat4 = (const float4*)feat;
  const float4* W4 = (const float4*)W;

  for (int k0 = 0; k0 < F; k0 += 32){
    #pragma unroll
    for (int qq = 0; qq < 2; ++qq){
      int q = t + qq*256;
      int m = q >> 3, kq = q & 7;
      int gm = m0 + m; if (gm > n_nodes - 1) gm = n_nodes - 1;
      float4 v = feat4[(size_t)gm*Fq + (k0 >> 2) + kq];
      *(float2*)&An[m][kq*4]     = make_float2(v.x, v.y);
      *(float2*)&An[m][kq*4 + 2] = make_float2(v.z, v.w);
    }
    #pragma unroll
    for (int qq = 0; qq < 2; ++qq){
      int q = t + qq*256;
      int d = q >> 3, kq = q & 7;
      float4 v = W4[(size_t)d*Fq + (k0 >> 2) + kq];
      *(float2*)&Bn[d][kq*4]     = make_float2(v.x, v.y);
      *(float2*)&Bn[d][kq*4 + 2] = make_float2(v.z, v.w);
    }
    __syncthreads();
    #pragma unroll 8
    for (int kk2 = 0; kk2 < 16; ++kk2){
      float2 a2[4], b2[4];
      #pragma unroll
      for (int i = 0; i < 4; ++i) a2[i] = *(const float2*)&An[tx + 16*i][kk2*2];
      #pragma unroll
      for (int j = 0; j < 4; ++j) b2[j] = *(const float2*)&Bn[ty*4 + j][kk2*2];
      #pragma unroll
      for (int i = 0; i < 4; ++i)
        #pragma unroll
        for (int j = 0; j < 4; ++j)
          acc[i][j] += a2[i].x*b2[j].x + a2[i].y*b2[j].y;
    }
    __syncthreads();
  }

  float4 bv = *(const float4*)&bias[ty*4];
  #pragma unroll
  for (int i = 0; i < 4; ++i){
    int gm = m0 + tx + 16*i;
    if (gm < n_nodes){
      union { __half2 h2[2]; uint2 u; } pk;
      pk.h2[0] = __floats2half2_rn(acc[i][0] + bv.x, acc[i][1] + bv.y);
      pk.h2[1] = __floats2half2_rn(acc[i][2] + bv.z, acc[i][3] + bv.w);
      *(uint2*)&tf16[(size_t)idx[gm]*HID + ty*4] = pk.u;
    }
  }
}

// ---- P = tf16 @ A.T per metapath/position, stored f16 ----
__global__ __launch_bounds__(256) void k_pmat(const __half* __restrict__ tf16,
                                              const float* __restrict__ A,
                                              __half* __restrict__ P){
  __shared__ float tfl[64][65];
  __shared__ float Al[48][65];
  int t = threadIdx.x;
  int n0 = blockIdx.x * 64;
  for (int q = t; q < 3072; q += 256) Al[q >> 6][q & 63] = A[q];
  const __half2* tfh = (const __half2*)(tf16 + (size_t)n0*64);
  for (int q = t; q < 2048; q += 256){
    int n = q >> 5, dq = q & 31;
    float2 v = make_float2(0.f, 0.f);
    if (n0 + n < NNODES) v = __half22float2(tfh[n*32 + dq]);
    tfl[n][dq*2] = v.x; tfl[n][dq*2+1] = v.y;
  }
  __syncthreads();
  int nl = t >> 2, q = t & 3;
  float s[12];
  #pragma unroll
  for (int c = 0; c < 12; ++c) s[c] = 0.f;
  #pragma unroll 4
  for (int d = 0; d < 64; ++d){
    float tv = tfl[nl][d];
    #pragma unroll
    for (int c = 0; c < 12; ++c) s[c] += tv * Al[q*12 + c][d];
  }
  int gn = n0 + nl;
  if (gn < NNODES){
    #pragma unroll
    for (int c = 0; c < 12; ++c){
      int cg = q*12 + c;
      int p = cg >= 24;
      int w = cg - p*24;
      P[(size_t)p*2400000 + (size_t)gn*24 + w] = __float2half(s[c]);
    }
  }
}

// ---- zero int buffer ----
__global__ void k_zeroi(int* __restrict__ p, int n){
  int t = blockIdx.x*blockDim.x + threadIdx.x;
  if (t < n) p[t] = 0;
}

// ---- histograms: dst (both p) + tgt (both p) ----
__global__ void k_hist3(const int* __restrict__ d0, const int* __restrict__ d1,
                        const int* __restrict__ t0, const int* __restrict__ t1,
                        int* __restrict__ counts, int* __restrict__ cntt){
  int e = blockIdx.x*blockDim.x + threadIdx.x;
  if (e < NE) atomicAdd(&counts[d0[e]], 1);
  else if (e < 2*NE) atomicAdd(&counts[NG + d1[e-NE]], 1);
  else if (e < 2*NE + NB) atomicAdd(&cntt[t0[e-2*NE]], 1);
  else if (e < 2*NE + 2*NB) atomicAdd(&cntt[NG + t1[e-2*NE-NB]], 1);
}

// ---- exclusive scan over 16384 counts; also zero cursors ----
__global__ __launch_bounds__(1024) void k_scan(const int* __restrict__ counts,
                                               int* __restrict__ offs,
                                               int* __restrict__ curs){
  __shared__ int lds[1024];
  int t = threadIdx.x;
  int base = t*16;
  int v[16]; int sum = 0;
  #pragma unroll
  for (int i = 0; i < 16; ++i){ v[i] = counts[base+i]; sum += v[i]; }
  lds[t] = sum;
  __syncthreads();
  for (int off = 1; off < 1024; off <<= 1){
    int x = (t >= off) ? lds[t-off] : 0;
    __syncthreads();
    lds[t] += x;
    __syncthreads();
  }
  int excl = lds[t] - sum;
  #pragma unroll
  for (int i = 0; i < 16; ++i){ offs[base+i] = excl; excl += v[i]; curs[base+i] = 0; }
  if (t == 1023) offs[2*NG] = excl;
}

// ---- scatter both metapaths' edges into dst-sorted order ----
__global__ void k_scatter2(const int* __restrict__ m0, const int* __restrict__ d0,
                           const int* __restrict__ m1, const int* __restrict__ d1,
                           const int* __restrict__ offs, int* __restrict__ curs,
                           int4* __restrict__ sorted){
  int e = blockIdx.x*blockDim.x + threadIdx.x;
  if (e >= 2*NE) return;
  const int* mp; int d;
  if (e < NE){ mp = m0 + (size_t)e*3; d = d0[e]; }
  else { mp = m1 + (size_t)(e-NE)*3; d = NG + d1[e-NE]; }
  int pos = offs[d] + atomicAdd(&curs[d], 1);
  sorted[pos] = make_int4(mp[0], mp[1], mp[2], 0);
}

// ---- fused per-segment softmax-agg; stores elu(ft) as f16 ----
__global__ __launch_bounds__(64) void k_seg(const __half* __restrict__ tf16,
                                            const __half* __restrict__ P,
                                            const int4* __restrict__ sorted,
                                            const int* __restrict__ offs,
                                            const float* __restrict__ finals,
                                            __half* __restrict__ ft16o){
  int bid = blockIdx.x;
  int p = bid >> 13;
  int lane = threadIdx.x;
  int hw = lane >> 5, j = lane & 31;
  int start = offs[bid], end = offs[bid+1];
  __half2* ftw = (__half2*)(ft16o + (size_t)bid*512);
  if (start == end){
    #pragma unroll
    for (int kk = 0; kk < 4; ++kk) ftw[(hw*4+kk)*32 + j] = __floats2half2_rn(0.f, 0.f);
    return;
  }
  const float2* F2 = (const float2*)(finals + p*192);
  float2 f0 = F2[j], f1 = F2[32 + j];
  const __half2* tfh = (const __half2*)tf16;
  const __half* Pp = P + (size_t)p*2400000;

  __shared__ int4 ndb[64];
  __shared__ float wb[64][8];

  float s[8], ur[8], ui[8];
  #pragma unroll
  for (int k = 0; k < 8; ++k){ s[k] = 0.f; ur[k] = 0.f; ui[k] = 0.f; }

  for (int c = start; c < end; c += 64){
    int n = end - c; if (n > 64) n = 64;
    if (lane < n){
      int4 nd = sorted[c + lane];
      ndb[lane] = nd;
      float4 rA = *(const float4*)(Pp + (size_t)nd.x*24);
      float4 rB = *(const float4*)(Pp + (size_t)nd.y*24 + 8);
      float4 rC = *(const float4*)(Pp + (size_t)nd.z*24 + 16);
      const __half2* ha = (const __half2*)&rA;
      const __half2* hb = (const __half2*)&rB;
      const __half2* hc = (const __half2*)&rC;
      float w[8];
      #pragma unroll
      for (int m = 0; m < 4; ++m){
        float2 va = __half22float2(ha[m]);
        float2 vb = __half22float2(hb[m]);
        float2 vc = __half22float2(hc[m]);
        float x0 = va.x + vb.x + vc.x;
        float x1 = va.y + vb.y + vc.y;
        x0 = x0 > 0.f ? x0 : 0.01f*x0;
        x1 = x1 > 0.f ? x1 : 0.01f*x1;
        w[2*m]   = __expf(x0);
        w[2*m+1] = __expf(x1);
      }
      *(float4*)&wb[lane][0] = make_float4(w[0], w[1], w[2], w[3]);
      *(float4*)&wb[lane][4] = make_float4(w[4], w[5], w[6], w[7]);
    }
    __syncthreads();
    int cend = c + n;
    for (int i = c + hw; i < cend; i += 2){
      int e = i - c;
      int4 nd = ndb[e];
      float4 wlo = *(const float4*)&wb[e][0];
      float4 whi = *(const float4*)&wb[e][4];
      float2 v0 = __half22float2(tfh[(size_t)nd.x*32 + j]);
      float2 v1 = __half22float2(tfh[(size_t)nd.y*32 + j]);
      float2 v2 = __half22float2(tfh[(size_t)nd.z*32 + j]);
      float hre = (v0.x*f0.x - v0.y*f0.y) + (v1.x*f1.x - v1.y*f1.y) + v2.x;
      float him = (v0.x*f0.y + v0.y*f0.x) + (v1.x*f1.y + v1.y*f1.x) + v2.y;
      ur[0] += wlo.x*hre; ui[0] += wlo.x*him; s[0] += wlo.x;
      ur[1] += wlo.y*hre; ui[1] += wlo.y*him; s[1] += wlo.y;
      ur[2] += wlo.z*hre; ui[2] += wlo.z*him; s[2] += wlo.z;
      ur[3] += wlo.w*hre; ui[3] += wlo.w*him; s[3] += wlo.w;
      ur[4] += whi.x*hre; ui[4] += whi.x*him; s[4] += whi.x;
      ur[5] += whi.y*hre; ui[5] += whi.y*him; s[5] += whi.y;
      ur[6] += whi.z*hre; ui[6] += whi.z*him; s[6] += whi.z;
      ur[7] += whi.w*hre; ui[7] += whi.w*him; s[7] += whi.w;
    }
    __syncthreads();
  }
  #pragma unroll
  for (int k = 0; k < 8; ++k){
    ur[k] += __shfl_xor(ur[k], 32);
    ui[k] += __shfl_xor(ui[k], 32);
    s[k]  += __shfl_xor(s[k], 32);
  }
  #pragma unroll
  for (int kk = 0; kk < 4; ++kk){
    int k = hw*4 + kk;
    float inv = 1.f / (3.f * s[k]);
    float re = ur[k]*inv, im = ui[k]*inv;
    re = re > 0.f ? re : expm1f(re);    // elu fused here
    im = im > 0.f ? im : expm1f(im);
    ftw[k*32 + j] = __floats2half2_rn(re, im);
  }
}

// ---- s1 via MFMA: acc[p][d] = sum_g cnt[p][g]*tanh(ft16o[p][g] @ fc1h.T + b)[d]
// 512 blocks (p*256+rb), 256 threads = 4 waves; wave: 16 rows x 64 cols.
// A,B fragments loaded directly from global (L2-hot), no LDS.
__global__ __launch_bounds__(256) void k_s1g(const __half* __restrict__ ft16o,
                                             const int* __restrict__ cntt,
                                             const __half* __restrict__ fc1h,
                                             const float* __restrict__ fc1_b,
                                             float* __restrict__ acc_p){
  int bid = blockIdx.x;
  int p  = bid >> 8;
  int rb = bid & 255;
  int t = threadIdx.x;
  int w = t >> 6, l = t & 63;
  int rowbase = rb*32 + (w & 1)*16;      // segment rows for this wave
  int colbase = (w >> 1)*64;             // 4 col-tiles of 16
  int lr = l & 15, lk = l >> 4;

  const half8v* Ab = (const half8v*)(ft16o + ((size_t)p*NG + rowbase)*512);
  f32x4 acc[4] = {{0.f,0.f,0.f,0.f},{0.f,0.f,0.f,0.f},
                  {0.f,0.f,0.f,0.f},{0.f,0.f,0.f,0.f}};

  #pragma unroll 4
  for (int kk = 0; kk < 16; ++kk){
    half8v a = Ab[(size_t)lr*64 + kk*4 + lk];   // A[row=lr][k=kk*32+lk*8..+7]
    #pragma unroll
    for (int ct = 0; ct < 4; ++ct){
      const half8v* Bb = (const half8v*)(fc1h + (size_t)(colbase + ct*16 + lr)*512);
      half8v b = Bb[kk*4 + lk];                 // B[k][col=..+lr]
      acc[ct] = __builtin_amdgcn_mfma_f32_16x16x32_f16(a, b, acc[ct], 0, 0, 0);
    }
  }

  // epilogue: C/D layout col=lane&15, row=(lane>>4)*4+reg (m89-verified)
  float cf[4];
  #pragma unroll
  for (int r = 0; r < 4; ++r)
    cf[r] = (float)cntt[p*NG + rowbase + lk*4 + r];
  #pragma unroll
  for (int ct = 0; ct < 4; ++ct){
    int col = colbase + ct*16 + lr;
    float bv = fc1_b[col];
    float sv = 0.f;
    #pragma unroll
    for (int r = 0; r < 4; ++r)
      sv += cf[r] * tanhf(acc[ct][r] + bv);
    sv += __shfl_xor(sv, 16);
    sv += __shfl_xor(sv, 32);
    if (l < 16) atomicAdd(&acc_p[p*128 + col], sv);
  }
}

// ---- beta softmax over 2 metapaths ----
__global__ void k_beta(const float* __restrict__ acc, const float* __restrict__ fc2_w,
                       float* __restrict__ beta){
  int t = threadIdx.x;  // 64
  float s0 = acc[t]*fc2_w[t] + acc[t+64]*fc2_w[t+64];
  float s1 = acc[128+t]*fc2_w[t] + acc[192+t]*fc2_w[t+64];
  #pragma unroll
  for (int mask = 1; mask < 64; mask <<= 1){
    s0 += __shfl_xor(s0, mask, 64);
    s1 += __shfl_xor(s1, mask, 64);
  }
  if (t == 0){
    float z0 = s0 / (float)NB, z1 = s1 / (float)NB;
    float mz = fmaxf(z0, z1);
    float e0 = expf(z0 - mz), e1 = expf(z1 - mz);
    float inv = 1.f / (e0 + e1);
    beta[0] = e0*inv; beta[1] = e1*inv;
  }
}

// ---- hagg + logits (ft already elu'd, f16) ----
__global__ void k_final(const __half* __restrict__ ft0, const __half* __restrict__ ft1,
                        const int* __restrict__ tgt0, const int* __restrict__ tgt1,
                        const float* __restrict__ beta, const float* __restrict__ fc_w,
                        const float* __restrict__ fc_b, float* __restrict__ d_out){
  __shared__ float lds[512];
  int b = blockIdx.x, t = threadIdx.x;  // 512 threads
  float b0 = beta[0], b1 = beta[1];
  int g0 = tgt0[b], g1 = tgt1[b];
  float v0 = __half2float(ft0[(size_t)g0*512 + t]);
  float v1 = __half2float(ft1[(size_t)g1*512 + t]);
  float h = b0*v0 + b1*v1;
  lds[t] = h;
  d_out[(size_t)NB*OUTD + (size_t)b*512 + t] = h;
  __syncthreads();
  int o = t >> 5, j = t & 31;
  float s = 0.f;
  const float* w = fc_w + o*512;
  for (int d = j; d < 512; d += 32) s += lds[d]*w[d];
  #pragma unroll
  for (int mask = 1; mask < 32; mask <<= 1) s += __shfl_xor(s, mask, 32);
  if (j == 0) d_out[(size_t)b*OUTD + o] = s + fc_b[o];
}

extern "C" void kernel_launch(void* const* d_in, const int* in_sizes, int n_in,
                              void* d_out, int out_size, void* d_ws, size_t ws_size,
                              hipStream_t stream){
  const float* feat0  = (const float*)d_in[0];
  const float* feat1  = (const float*)d_in[1];
  const float* W0     = (const float*)d_in[2];
  const float* b0     = (const float*)d_in[3];
  const float* W1     = (const float*)d_in[4];
  const float* b1     = (const float*)d_in[5];
  const float* r_vec  = (const float*)d_in[6];
  const float* attn0  = (const float*)d_in[7];
  const float* attn1  = (const float*)d_in[8];
  const float* fc1_w  = (const float*)d_in[9];
  const float* fc1_b  = (const float*)d_in[10];
  const float* fc2_w  = (const float*)d_in[11];
  const float* fc_w   = (const float*)d_in[12];
  const float* fc_b   = (const float*)d_in[13];
  const int*   idx0   = (const int*)d_in[14];
  const int*   idx1   = (const int*)d_in[15];
  const int*   mpi0   = (const int*)d_in[16];
  const int*   mdst0  = (const int*)d_in[17];
  const int*   mtgt0  = (const int*)d_in[18];
  const int*   mpi1   = (const int*)d_in[19];
  const int*   mdst1  = (const int*)d_in[20];
  const int*   mtgt1  = (const int*)d_in[21];

  float* ws      = (float*)d_ws;
  __half* tf16   = (__half*)(ws + OFF_TF16);
  float* finals  = ws + OFF_FINALS;
  float* Amat    = ws + OFF_A;
  float* acc     = ws + OFF_ACC;
  float* beta    = ws + OFF_BETA;
  __half* fc1h   = (__half*)(ws + OFF_FC1H);
  __half* P      = (__half*)(ws + OFF_P);
  int4*  sorted  = (int4*)(ws + OFF_SORTED);
  int*   counts  = (int*)(ws + OFF_COUNTS);
  int*   cntt    = (int*)(ws + OFF_CNTT);
  int*   curs    = (int*)(ws + OFF_CURS);
  int*   offs    = (int*)(ws + OFF_OFFS);
  __half* ft16o  = (__half*)(ws + OFF_FT16);
  __half* ft0h   = ft16o;
  __half* ft1h   = ft16o + (size_t)NG*512;

  k_prep<<<1, 256, 0, stream>>>(r_vec, attn0, attn1, finals, Amat, acc, beta);
  k_cvtw<<<256, 256, 0, stream>>>(fc1_w, fc1h);
  k_zeroi<<<128, 256, 0, stream>>>(counts, 4*NG);   // counts + cntt (contiguous)
  k_hist3<<<(2*NE + 2*NB + 255)/256, 256, 0, stream>>>(mdst0, mdst1, mtgt0, mtgt1,
                                                       counts, cntt);
  k_scan<<<1, 1024, 0, stream>>>(counts, offs, curs);
  k_scatter2<<<(2*NE + 255)/256, 256, 0, stream>>>(mpi0, mdst0, mpi1, mdst1,
                                                   offs, curs, sorted);

  k_transform2<<<(NT0 + 63)/64 + (NT1 + 63)/64, 256, 0, stream>>>(
      feat0, W0, b0, idx0, feat1, W1, b1, idx1, tf16);
  k_pmat<<<(NNODES + 63)/64, 256, 0, stream>>>(tf16, Amat, P);

  k_seg<<<2*NG, 64, 0, stream>>>(tf16, P, sorted, offs, finals, ft16o);

  k_s1g<<<512, 256, 0, stream>>>(ft16o, cntt, fc1h, fc1_b, acc);
  k_beta<<<1, 64, 0, stream>>>(acc, fc2_w, beta);
  k_final<<<NB, 512, 0, stream>>>(ft0h, ft1h, mtgt0, mtgt1, beta, fc_w, fc_b,
                                  (float*)d_out);
}